// Round 2
// baseline (1567.722 us; speedup 1.0000x reference)
//
#include <hip/hip_runtime.h>

#define N_NODES 20000
#define CW_FLOATS 1024                 // 729 used, padded to 4 KiB
#define WCB_FLOATS (3*9*30*64)         // 51840 = repacked W_chem (wbody folded in)
#define NAB_FLOATS (N_NODES*32)        // 30 used per node, padded to 32

// ---------------------------------------------------------------------------
// Compile-time sparsity pattern of the combined 9x9x9 real-Wigner table.
// 83 entries, grouped by L (the u / l1 index). Values computed on-device.
// ---------------------------------------------------------------------------
constexpr int ENT_OFF[10] = {0, 9, 19, 27, 37, 45, 55, 65, 75, 83};
constexpr int ENT_M[83] = {
  0,1,2,3,4,5,6,7,8,            // L=0
  0,1,3,2,1,1,4,5,6,8,          // L=1
  0,2,1,3,2,5,7,6,              // L=2
  0,3,1,2,3,3,4,7,6,8,          // L=3
  0,4,1,3,6,4,5,7,              // L=4
  0,5,1,2,6,5,5,8,4,7,          // L=5
  0,6,1,2,3,6,5,7,4,8,          // L=6
  0,7,2,3,6,7,7,8,4,5,          // L=7
  0,8,1,3,6,8,5,7               // L=8
};
constexpr int ENT_S[83] = {
  0,1,2,3,4,5,6,7,8,
  1,0,4,5,6,8,3,2,1,1,
  2,0,5,7,6,1,3,2,
  3,0,4,7,6,8,1,2,3,3,
  4,0,3,1,4,6,7,5,
  5,0,2,1,5,6,8,5,7,4,
  6,0,1,2,3,6,5,7,4,8,
  7,0,3,2,7,6,8,7,5,4,
  8,0,1,3,8,6,5,7
};

// ---------------------------------------------------------------------------
// Init kernel: fp64 replication of the reference's Wigner-3j construction,
// W_chem repack (with wbody folded in), and scrambled node_attr precompute.
// ---------------------------------------------------------------------------
struct cplx { double re, im; };
__device__ inline cplx cmul(cplx a, cplx b){ return {a.re*b.re - a.im*b.im, a.re*b.im + a.im*b.re}; }

__device__ inline double factd(int n){ double r = 1.0; for (int i = 2; i <= n; ++i) r *= (double)i; return r; }

__device__ double cg_coeff(int j1,int m1,int j2,int m2,int j3,int m3){
  if (m3 != m1 + m2) return 0.0;
  int vmin = -j1 + j2 + m3;
  if (-j1 + m1 > vmin) vmin = -j1 + m1;
  if (vmin < 0) vmin = 0;
  int vmax = j2 + j3 + m1;
  if (j3 - j1 + j2 < vmax) vmax = j3 - j1 + j2;
  if (j3 + m3 < vmax) vmax = j3 + m3;
  double c = sqrt((double)(2*j3+1) *
      (factd(j3+j1-j2)*factd(j3-j1+j2)*factd(j1+j2-j3)*factd(j3+m3)*factd(j3-m3)) /
      (factd(j1+j2+j3+1)*factd(j1-m1)*factd(j1+m1)*factd(j2-m2)*factd(j2+m2)));
  double s = 0.0;
  for (int v = vmin; v <= vmax; ++v){
    double t = (factd(j2+j3+m1-v)*factd(j1-m1+v)) /
               (factd(v)*factd(j3-j1+j2-v)*factd(j3+m3-v)*factd(v+j1-j2-m3));
    s += ((v + j2 + m2) & 1) ? -t : t;
  }
  return c * s;
}

__device__ cplx qmat(int l, int r, int c){
  cplx v = {0.0, 0.0};
  const double is2 = 0.70710678118654752440;
  const int m = r - l;
  if (m < 0){
    if (c == 2*l - r)      v = { is2, 0.0 };
    else if (c == r)       v = { 0.0, -is2 };
  } else if (m == 0){
    if (c == l)            v = { 1.0, 0.0 };
  } else {
    const double sg = (m & 1) ? -1.0 : 1.0;
    if (c == r)            v = { sg*is2, 0.0 };
    else if (c == 2*l - r) v = { 0.0, sg*is2 };
  }
  if (l == 1)      v = { v.im, -v.re };   // * (-i)
  else if (l == 2) v = { -v.re, -v.im };  // * (-i)^2 = -1
  return v;
}

__global__ void nn3b_init_kernel(const float* __restrict__ node_attr,
                                 const float* __restrict__ W_chem,
                                 const float* __restrict__ wbody,
                                 float* __restrict__ cw,
                                 float* __restrict__ wcB,
                                 float* __restrict__ nab)
{
  const int t = blockIdx.x * 256 + threadIdx.x;

  // Job A: combined Wigner table (729 entries).
  if (t < CW_FLOATS){
    float val = 0.0f;
    if (t < 729){
      const int S = t % 9, M = (t / 9) % 9, L = t / 81;
      const int l1 = (L==0)?0:((L<4)?1:2);
      const int l2 = (M==0)?0:((M<4)?1:2);
      const int l3 = (S==0)?0:((S<4)?1:2);
      const int a  = L - ((l1==0)?0:((l1==1)?1:4));
      const int b  = M - ((l2==0)?0:((l2==1)?1:4));
      const int cc = S - ((l3==0)?0:((l3==1)?1:4));
      const int lo = (l1 > l2) ? l1 - l2 : l2 - l1;
      if (l3 >= lo && l3 <= l1 + l2 && (((l1 + l2 + l3) & 1) == 0)){
        cplx acc = {0.0, 0.0};
        for (int i = 0; i < 2*l1+1; ++i){
          cplx q1 = qmat(l1, i, a);
          if (q1.re == 0.0 && q1.im == 0.0) continue;
          for (int k = 0; k < 2*l2+1; ++k){
            cplx q2 = qmat(l2, k, b);
            if (q2.re == 0.0 && q2.im == 0.0) continue;
            cplx q12 = cmul(q1, q2);
            for (int n = 0; n < 2*l3+1; ++n){
              cplx q3 = qmat(l3, n, cc);
              if (q3.re == 0.0 && q3.im == 0.0) continue;
              double cg = cg_coeff(l1, i-l1, l2, k-l2, l3, n-l3);
              if (cg == 0.0) continue;
              cplx q3c = { q3.re, -q3.im };
              cplx term = cmul(q12, q3c);
              acc.re += term.re * cg;
              acc.im += term.im * cg;
            }
          }
        }
        const double w = acc.re / sqrt((double)(2*l3+1));  // su2_cg's 1/sqrt(2l3+1)
        val = (float)(w * 0.10540925533894598);            // fold 1/sqrt(30)/sqrt(3)
      }
    }
    cw[t] = val;
  }

  // Job B: repack W_chem -> wcB[b][d][k][c] = W_chem[k, d*192+3c+b] * wbody[b]
  const int tb = t - CW_FLOATS;
  if (tb >= 0 && tb < WCB_FLOATS){
    const int c = tb & 63;
    const int k = (tb >> 6) % 30;
    const int d = (tb / 1920) % 9;
    const int b = tb / 17280;
    wcB[tb] = W_chem[k*1728 + d*192 + 3*c + b] * wbody[b];
  }

  // Job C: scrambled chem rows, padded to 32 floats/node for scalar loads
  const int tc = t - (CW_FLOATS + WCB_FLOATS);
  if (tc >= 0 && tc < NAB_FLOATS){
    const int n = tc >> 5;
    const int k = tc & 31;
    float v = 0.0f;
    if (k < 30){
      const int i = 30*n + k;
      v = node_attr[(i % N_NODES)*10 + ((i / N_NODES) % 10)];
    }
    nab[tc] = v;
  }
}

// ---------------------------------------------------------------------------
// Main kernel: 256 threads = 4 waves; each wave owns 4 nodes; each thread owns
// one channel c for 4 nodes (amortizes the wcB loads 4x). No launch_bounds:
// let the allocator take ~110-160 VGPRs for the o/v/u live set — the R1 spill
// (VGPR=64 cap -> 3.2 GB of scratch churn, VALUBusy 4.8%) came from capping it.
// nab/cw are wave-uniform -> SGPR loads; wcB reads are 256 B/wave coalesced.
// ---------------------------------------------------------------------------
__global__ void nn3b_main_kernel(const float* __restrict__ nbody,
                                 const float* __restrict__ cw,
                                 const float* __restrict__ wcB,
                                 const float* __restrict__ nab,
                                 float* __restrict__ out)
{
  const int c  = threadIdx.x & 63;
  const int g  = __builtin_amdgcn_readfirstlane((int)(threadIdx.x >> 6)); // force SGPR
  const int n0 = blockIdx.x * 16 + g * 4;

  float o[4][9];
  #pragma unroll
  for (int l = 0; l < 4; ++l)
    #pragma unroll
    for (int s = 0; s < 9; ++s) o[l][s] = 0.0f;

  const float* nab_base = nab + (size_t)n0 * 32;

  #pragma unroll 1     // keep body-order loop rolled: 3x smaller code, same work
  for (int b = 0; b < 3; ++b){
    float v[4][9];
    #pragma unroll
    for (int l = 0; l < 4; ++l){
      const float* vp = nbody + ((size_t)b*N_NODES + (n0 + l))*576 + c*9;
      #pragma unroll
      for (int m = 0; m < 9; ++m) v[l][m] = vp[m];
    }
    const float* wcb_b = wcB + b*(9*30*64);

    #pragma unroll
    for (int dL = 0; dL < 9; ++dL){
      float u[4] = {0.f, 0.f, 0.f, 0.f};
      const float* wp = wcb_b + dL*(30*64) + c;
      #pragma unroll
      for (int k = 0; k < 30; ++k){
        const float w = wp[k*64];
        #pragma unroll
        for (int l = 0; l < 4; ++l)
          u[l] = fmaf(nab_base[l*32 + k], w, u[l]);
      }
      #pragma unroll
      for (int e = ENT_OFF[dL]; e < ENT_OFF[dL+1]; ++e){
        const float cc = cw[(dL*9 + ENT_M[e])*9 + ENT_S[e]];
        #pragma unroll
        for (int l = 0; l < 4; ++l)
          o[l][ENT_S[e]] = fmaf(cc * u[l], v[l][ENT_M[e]], o[l][ENT_S[e]]);
      }
    }
  }

  #pragma unroll
  for (int l = 0; l < 4; ++l){
    float* op = out + (size_t)(n0 + l)*576 + c*9;
    #pragma unroll
    for (int s = 0; s < 9; ++s) op[s] = o[l][s];
  }
}

extern "C" void kernel_launch(void* const* d_in, const int* in_sizes, int n_in,
                              void* d_out, int out_size, void* d_ws, size_t ws_size,
                              hipStream_t stream)
{
  const float* nbody     = (const float*)d_in[0];  // (3, 20000, 64, 9) f32
  const float* node_attr = (const float*)d_in[1];  // (20000, 10) f32
  const float* W_chem    = (const float*)d_in[2];  // (30, 1728) f32
  const float* wbody     = (const float*)d_in[3];  // (3, 1) f32
  float* out = (float*)d_out;                      // (20000, 64, 9) f32

  float* cw  = (float*)d_ws;          // 1024 f
  float* wcB = cw + CW_FLOATS;        // 51840 f
  float* nab = wcB + WCB_FLOATS;      // 640000 f   (total ~2.65 MiB of ws)

  const int init_items  = CW_FLOATS + WCB_FLOATS + NAB_FLOATS;
  const int init_blocks = (init_items + 255) / 256;
  nn3b_init_kernel<<<init_blocks, 256, 0, stream>>>(node_attr, W_chem, wbody, cw, wcB, nab);

  nn3b_main_kernel<<<N_NODES/16, 256, 0, stream>>>(nbody, cw, wcB, nab, out);
}

// Round 4
// 385.060 us; speedup vs baseline: 4.0714x; 4.0714x over previous
//
#include <hip/hip_runtime.h>

#define N_NODES 20000
#define CW_FLOATS 1024                 // 729 used, padded to 4 KiB
#define WCB_FLOATS (3*9*30*64)         // 51840 = repacked W_chem (wbody folded in)
#define NAB_FLOATS (N_NODES*32)        // 30 used per node, padded to 32

// ---------------------------------------------------------------------------
// Init kernel: fp64 replication of the reference's Wigner-3j construction,
// W_chem repack (with wbody folded in), and scrambled node_attr precompute.
// (Unchanged from R1/R2 — numerically validated, absmax 0.03.)
// ---------------------------------------------------------------------------
struct cplx { double re, im; };
__device__ inline cplx cmul(cplx a, cplx b){ return {a.re*b.re - a.im*b.im, a.re*b.im + a.im*b.re}; }

__device__ inline double factd(int n){ double r = 1.0; for (int i = 2; i <= n; ++i) r *= (double)i; return r; }

__device__ double cg_coeff(int j1,int m1,int j2,int m2,int j3,int m3){
  if (m3 != m1 + m2) return 0.0;
  int vmin = -j1 + j2 + m3;
  if (-j1 + m1 > vmin) vmin = -j1 + m1;
  if (vmin < 0) vmin = 0;
  int vmax = j2 + j3 + m1;
  if (j3 - j1 + j2 < vmax) vmax = j3 - j1 + j2;
  if (j3 + m3 < vmax) vmax = j3 + m3;
  double c = sqrt((double)(2*j3+1) *
      (factd(j3+j1-j2)*factd(j3-j1+j2)*factd(j1+j2-j3)*factd(j3+m3)*factd(j3-m3)) /
      (factd(j1+j2+j3+1)*factd(j1-m1)*factd(j1+m1)*factd(j2-m2)*factd(j2+m2)));
  double s = 0.0;
  for (int v = vmin; v <= vmax; ++v){
    double t = (factd(j2+j3+m1-v)*factd(j1-m1+v)) /
               (factd(v)*factd(j3-j1+j2-v)*factd(j3+m3-v)*factd(v+j1-j2-m3));
    s += ((v + j2 + m2) & 1) ? -t : t;
  }
  return c * s;
}

__device__ cplx qmat(int l, int r, int c){
  cplx v = {0.0, 0.0};
  const double is2 = 0.70710678118654752440;
  const int m = r - l;
  if (m < 0){
    if (c == 2*l - r)      v = { is2, 0.0 };
    else if (c == r)       v = { 0.0, -is2 };
  } else if (m == 0){
    if (c == l)            v = { 1.0, 0.0 };
  } else {
    const double sg = (m & 1) ? -1.0 : 1.0;
    if (c == r)            v = { sg*is2, 0.0 };
    else if (c == 2*l - r) v = { 0.0, sg*is2 };
  }
  if (l == 1)      v = { v.im, -v.re };   // * (-i)
  else if (l == 2) v = { -v.re, -v.im };  // * (-i)^2 = -1
  return v;
}

__global__ void nn3b_init_kernel(const float* __restrict__ node_attr,
                                 const float* __restrict__ W_chem,
                                 const float* __restrict__ wbody,
                                 float* __restrict__ cw,
                                 float* __restrict__ wcB,
                                 float* __restrict__ nab)
{
  const int t = blockIdx.x * 256 + threadIdx.x;

  // Job A: combined Wigner table (729 entries).
  if (t < CW_FLOATS){
    float val = 0.0f;
    if (t < 729){
      const int S = t % 9, M = (t / 9) % 9, L = t / 81;
      const int l1 = (L==0)?0:((L<4)?1:2);
      const int l2 = (M==0)?0:((M<4)?1:2);
      const int l3 = (S==0)?0:((S<4)?1:2);
      const int a  = L - ((l1==0)?0:((l1==1)?1:4));
      const int b  = M - ((l2==0)?0:((l2==1)?1:4));
      const int cc = S - ((l3==0)?0:((l3==1)?1:4));
      const int lo = (l1 > l2) ? l1 - l2 : l2 - l1;
      if (l3 >= lo && l3 <= l1 + l2 && (((l1 + l2 + l3) & 1) == 0)){
        cplx acc = {0.0, 0.0};
        for (int i = 0; i < 2*l1+1; ++i){
          cplx q1 = qmat(l1, i, a);
          if (q1.re == 0.0 && q1.im == 0.0) continue;
          for (int k = 0; k < 2*l2+1; ++k){
            cplx q2 = qmat(l2, k, b);
            if (q2.re == 0.0 && q2.im == 0.0) continue;
            cplx q12 = cmul(q1, q2);
            for (int n = 0; n < 2*l3+1; ++n){
              cplx q3 = qmat(l3, n, cc);
              if (q3.re == 0.0 && q3.im == 0.0) continue;
              double cg = cg_coeff(l1, i-l1, l2, k-l2, l3, n-l3);
              if (cg == 0.0) continue;
              cplx q3c = { q3.re, -q3.im };
              cplx term = cmul(q12, q3c);
              acc.re += term.re * cg;
              acc.im += term.im * cg;
            }
          }
        }
        const double w = acc.re / sqrt((double)(2*l3+1));  // su2_cg's 1/sqrt(2l3+1)
        val = (float)(w * 0.10540925533894598);            // fold 1/sqrt(30)/sqrt(3)
      }
    }
    cw[t] = val;
  }

  // Job B: repack W_chem -> wcB[b][d][k][c] = W_chem[k, d*192+3c+b] * wbody[b]
  const int tb = t - CW_FLOATS;
  if (tb >= 0 && tb < WCB_FLOATS){
    const int c = tb & 63;
    const int k = (tb >> 6) % 30;
    const int d = (tb / 1920) % 9;
    const int b = tb / 17280;
    wcB[tb] = W_chem[k*1728 + d*192 + 3*c + b] * wbody[b];
  }

  // Job C: scrambled chem rows, padded to 32 floats/node for scalar loads
  const int tc = t - (CW_FLOATS + WCB_FLOATS);
  if (tc >= 0 && tc < NAB_FLOATS){
    const int n = tc >> 5;
    const int k = tc & 31;
    float v = 0.0f;
    if (k < 30){
      const int i = 30*n + k;
      v = node_attr[(i % N_NODES)*10 + ((i / N_NODES) % 10)];
    }
    nab[tc] = v;
  }
}

// ---------------------------------------------------------------------------
// Main kernel. Literal-index macro expansion (guarantees mem2reg promotion —
// the R1/R2 table-driven loops left o/v in scratch: 3.2 GB HBM churn).
// R3 post-mortem: the L=8 row was mistranscribed as (8,6,6),(8,8,8) — both
// mathematically ZERO (cos2φ·1·1 and cos³2φ integrate to 0) — while dropping
// the true entries (8,6,8),(8,8,6) (cos²2φ·1 ≠ 0). Verified against an
// independent φ-selection-rule derivation of all 83 entries AND the R2-passing
// table. Fixed here; everything else identical to R3.
// 256 threads = 4 waves; each thread owns channel c for 2 nodes (A,B).
// ---------------------------------------------------------------------------

// u for one dL: 30 FMAs per node, w shared between the 2 nodes.
#define UCOMP(DL)                                                         \
  {                                                                       \
    uA = 0.0f; uB = 0.0f;                                                 \
    const float* wp = wcb_b + (DL)*(30*64) + c;                           \
    _Pragma("unroll")                                                     \
    for (int k = 0; k < 30; ++k){                                         \
      const float w = wp[k*64];                                           \
      uA = fmaf(nabA[k], w, uA);                                          \
      uB = fmaf(nabB[k], w, uB);                                          \
    }                                                                     \
  }

// one tensor-product entry: o[S] += cw[DL,M,S] * u * v[M]   (literal indices)
#define E(DL,M,S)                                                         \
  {                                                                       \
    const float cc = cw[((DL)*9+(M))*9+(S)];                              \
    oA[S] = fmaf(cc * uA, vA[M], oA[S]);                                  \
    oB[S] = fmaf(cc * uB, vB[M], oB[S]);                                  \
  }

#define LD9(dst, p) { dst[0]=(p)[0]; dst[1]=(p)[1]; dst[2]=(p)[2];        \
                      dst[3]=(p)[3]; dst[4]=(p)[4]; dst[5]=(p)[5];        \
                      dst[6]=(p)[6]; dst[7]=(p)[7]; dst[8]=(p)[8]; }
#define ST9(p, src) { (p)[0]=src[0]; (p)[1]=src[1]; (p)[2]=src[2];        \
                      (p)[3]=src[3]; (p)[4]=src[4]; (p)[5]=src[5];        \
                      (p)[6]=src[6]; (p)[7]=src[7]; (p)[8]=src[8]; }

__global__ __launch_bounds__(256)
void nn3b_main_kernel(const float* __restrict__ nbody,
                      const float* __restrict__ cw,
                      const float* __restrict__ wcB,
                      const float* __restrict__ nab,
                      float* __restrict__ out)
{
  const int c  = threadIdx.x & 63;
  const int g  = __builtin_amdgcn_readfirstlane((int)(threadIdx.x >> 6)); // SGPR
  const int nA = blockIdx.x * 8 + g * 2;   // this wave's node pair
  const int nB = nA + 1;

  float oA[9] = {0,0,0,0,0,0,0,0,0};
  float oB[9] = {0,0,0,0,0,0,0,0,0};

  const float* nabA = nab + (size_t)nA * 32;
  const float* nabB = nab + (size_t)nB * 32;

  #pragma unroll 1   // keep body-order loop rolled: 3x smaller code
  for (int b = 0; b < 3; ++b){
    float vA[9], vB[9];
    {
      const float* pA = nbody + ((size_t)b*N_NODES + nA)*576 + c*9;
      const float* pB = nbody + ((size_t)b*N_NODES + nB)*576 + c*9;
      LD9(vA, pA);
      LD9(vB, pB);
    }
    const float* wcb_b = wcB + b*(9*30*64);
    float uA, uB;

    UCOMP(0)
    E(0,0,0) E(0,1,1) E(0,2,2) E(0,3,3) E(0,4,4) E(0,5,5) E(0,6,6) E(0,7,7) E(0,8,8)
    UCOMP(1)
    E(1,0,1) E(1,1,0) E(1,3,4) E(1,2,5) E(1,1,6) E(1,1,8) E(1,4,3) E(1,5,2) E(1,6,1) E(1,8,1)
    UCOMP(2)
    E(2,0,2) E(2,2,0) E(2,1,5) E(2,3,7) E(2,2,6) E(2,5,1) E(2,7,3) E(2,6,2)
    UCOMP(3)
    E(3,0,3) E(3,3,0) E(3,1,4) E(3,2,7) E(3,3,6) E(3,3,8) E(3,4,1) E(3,7,2) E(3,6,3) E(3,8,3)
    UCOMP(4)
    E(4,0,4) E(4,4,0) E(4,1,3) E(4,3,1) E(4,6,4) E(4,4,6) E(4,5,7) E(4,7,5)
    UCOMP(5)
    E(5,0,5) E(5,5,0) E(5,1,2) E(5,2,1) E(5,6,5) E(5,5,6) E(5,5,8) E(5,8,5) E(5,4,7) E(5,7,4)
    UCOMP(6)
    E(6,0,6) E(6,6,0) E(6,1,1) E(6,2,2) E(6,3,3) E(6,6,6) E(6,5,5) E(6,7,7) E(6,4,4) E(6,8,8)
    UCOMP(7)
    E(7,0,7) E(7,7,0) E(7,2,3) E(7,3,2) E(7,6,7) E(7,7,6) E(7,7,8) E(7,8,7) E(7,4,5) E(7,5,4)
    UCOMP(8)
    E(8,0,8) E(8,8,0) E(8,1,1) E(8,3,3) E(8,6,8) E(8,8,6) E(8,5,5) E(8,7,7)
  }

  {
    float* pA = out + (size_t)nA*576 + c*9;
    float* pB = out + (size_t)nB*576 + c*9;
    ST9(pA, oA);
    ST9(pB, oB);
  }
}

extern "C" void kernel_launch(void* const* d_in, const int* in_sizes, int n_in,
                              void* d_out, int out_size, void* d_ws, size_t ws_size,
                              hipStream_t stream)
{
  const float* nbody     = (const float*)d_in[0];  // (3, 20000, 64, 9) f32
  const float* node_attr = (const float*)d_in[1];  // (20000, 10) f32
  const float* W_chem    = (const float*)d_in[2];  // (30, 1728) f32
  const float* wbody     = (const float*)d_in[3];  // (3, 1) f32
  float* out = (float*)d_out;                      // (20000, 64, 9) f32

  float* cw  = (float*)d_ws;          // 1024 f
  float* wcB = cw + CW_FLOATS;        // 51840 f
  float* nab = wcB + WCB_FLOATS;      // 640000 f   (total ~2.65 MiB of ws)

  const int init_items  = CW_FLOATS + WCB_FLOATS + NAB_FLOATS;
  const int init_blocks = (init_items + 255) / 256;
  nn3b_init_kernel<<<init_blocks, 256, 0, stream>>>(node_attr, W_chem, wbody, cw, wcB, nab);

  nn3b_main_kernel<<<N_NODES/8, 256, 0, stream>>>(nbody, cw, wcB, nab, out);
}

// Round 5
// 374.382 us; speedup vs baseline: 4.1875x; 1.0285x over previous
//
#include <hip/hip_runtime.h>

#define N_NODES 20000
#define CW_FLOATS 1024                 // 729 used, padded to 4 KiB
#define WCB_FLOATS (3*9*30*64)         // 51840 = repacked W_chem (wbody folded in)
#define NAB_FLOATS (N_NODES*32)        // 30 used per node, padded to 32

// ---------------------------------------------------------------------------
// Init kernel: fp64 replication of the reference's Wigner-3j construction,
// W_chem repack (with wbody folded in), and scrambled node_attr precompute.
// (Unchanged — numerically validated, absmax 0.03.)
// ---------------------------------------------------------------------------
struct cplx { double re, im; };
__device__ inline cplx cmul(cplx a, cplx b){ return {a.re*b.re - a.im*b.im, a.re*b.im + a.im*b.re}; }

__device__ inline double factd(int n){ double r = 1.0; for (int i = 2; i <= n; ++i) r *= (double)i; return r; }

__device__ double cg_coeff(int j1,int m1,int j2,int m2,int j3,int m3){
  if (m3 != m1 + m2) return 0.0;
  int vmin = -j1 + j2 + m3;
  if (-j1 + m1 > vmin) vmin = -j1 + m1;
  if (vmin < 0) vmin = 0;
  int vmax = j2 + j3 + m1;
  if (j3 - j1 + j2 < vmax) vmax = j3 - j1 + j2;
  if (j3 + m3 < vmax) vmax = j3 + m3;
  double c = sqrt((double)(2*j3+1) *
      (factd(j3+j1-j2)*factd(j3-j1+j2)*factd(j1+j2-j3)*factd(j3+m3)*factd(j3-m3)) /
      (factd(j1+j2+j3+1)*factd(j1-m1)*factd(j1+m1)*factd(j2-m2)*factd(j2+m2)));
  double s = 0.0;
  for (int v = vmin; v <= vmax; ++v){
    double t = (factd(j2+j3+m1-v)*factd(j1-m1+v)) /
               (factd(v)*factd(j3-j1+j2-v)*factd(j3+m3-v)*factd(v+j1-j2-m3));
    s += ((v + j2 + m2) & 1) ? -t : t;
  }
  return c * s;
}

__device__ cplx qmat(int l, int r, int c){
  cplx v = {0.0, 0.0};
  const double is2 = 0.70710678118654752440;
  const int m = r - l;
  if (m < 0){
    if (c == 2*l - r)      v = { is2, 0.0 };
    else if (c == r)       v = { 0.0, -is2 };
  } else if (m == 0){
    if (c == l)            v = { 1.0, 0.0 };
  } else {
    const double sg = (m & 1) ? -1.0 : 1.0;
    if (c == r)            v = { sg*is2, 0.0 };
    else if (c == 2*l - r) v = { 0.0, sg*is2 };
  }
  if (l == 1)      v = { v.im, -v.re };   // * (-i)
  else if (l == 2) v = { -v.re, -v.im };  // * (-i)^2 = -1
  return v;
}

__global__ void nn3b_init_kernel(const float* __restrict__ node_attr,
                                 const float* __restrict__ W_chem,
                                 const float* __restrict__ wbody,
                                 float* __restrict__ cw,
                                 float* __restrict__ wcB,
                                 float* __restrict__ nab)
{
  const int t = blockIdx.x * 256 + threadIdx.x;

  // Job A: combined Wigner table (729 entries).
  if (t < CW_FLOATS){
    float val = 0.0f;
    if (t < 729){
      const int S = t % 9, M = (t / 9) % 9, L = t / 81;
      const int l1 = (L==0)?0:((L<4)?1:2);
      const int l2 = (M==0)?0:((M<4)?1:2);
      const int l3 = (S==0)?0:((S<4)?1:2);
      const int a  = L - ((l1==0)?0:((l1==1)?1:4));
      const int b  = M - ((l2==0)?0:((l2==1)?1:4));
      const int cc = S - ((l3==0)?0:((l3==1)?1:4));
      const int lo = (l1 > l2) ? l1 - l2 : l2 - l1;
      if (l3 >= lo && l3 <= l1 + l2 && (((l1 + l2 + l3) & 1) == 0)){
        cplx acc = {0.0, 0.0};
        for (int i = 0; i < 2*l1+1; ++i){
          cplx q1 = qmat(l1, i, a);
          if (q1.re == 0.0 && q1.im == 0.0) continue;
          for (int k = 0; k < 2*l2+1; ++k){
            cplx q2 = qmat(l2, k, b);
            if (q2.re == 0.0 && q2.im == 0.0) continue;
            cplx q12 = cmul(q1, q2);
            for (int n = 0; n < 2*l3+1; ++n){
              cplx q3 = qmat(l3, n, cc);
              if (q3.re == 0.0 && q3.im == 0.0) continue;
              double cg = cg_coeff(l1, i-l1, l2, k-l2, l3, n-l3);
              if (cg == 0.0) continue;
              cplx q3c = { q3.re, -q3.im };
              cplx term = cmul(q12, q3c);
              acc.re += term.re * cg;
              acc.im += term.im * cg;
            }
          }
        }
        const double w = acc.re / sqrt((double)(2*l3+1));  // su2_cg's 1/sqrt(2l3+1)
        val = (float)(w * 0.10540925533894598);            // fold 1/sqrt(30)/sqrt(3)
      }
    }
    cw[t] = val;
  }

  // Job B: repack W_chem -> wcB[b][d][k][c] = W_chem[k, d*192+3c+b] * wbody[b]
  const int tb = t - CW_FLOATS;
  if (tb >= 0 && tb < WCB_FLOATS){
    const int c = tb & 63;
    const int k = (tb >> 6) % 30;
    const int d = (tb / 1920) % 9;
    const int b = tb / 17280;
    wcB[tb] = W_chem[k*1728 + d*192 + 3*c + b] * wbody[b];
  }

  // Job C: scrambled chem rows, padded to 32 floats/node for scalar loads
  const int tc = t - (CW_FLOATS + WCB_FLOATS);
  if (tc >= 0 && tc < NAB_FLOATS){
    const int n = tc >> 5;
    const int k = tc & 31;
    float v = 0.0f;
    if (k < 30){
      const int i = 30*n + k;
      v = node_attr[(i % N_NODES)*10 + ((i / N_NODES) % 10)];
    }
    nab[tc] = v;
  }
}

// ---------------------------------------------------------------------------
// Main kernel, R5: LDS-staged weights.
// R4 was latency-bound (VALUBusy 32%, HBM 8%, 190 us): 810 global wcB loads
// per thread streamed a 69 KB/b slab through 32 KB L1 at ~200 cyc latency with
// only 3 waves/SIMD resident. Fix: 512-thread blocks (8 waves, 16 nodes)
// cooperatively stage wcB into LDS in 3-dL chunks (23 KB static), weights then
// come from LDS (free 2-way bank aliasing at stride-1 lane=c). u-accumulation
// split into 2 half-chains per node -> 4 independent FMA chains in flight.
// All array indices remain literal macros (mem2reg guarantee from R3/R4).
// ---------------------------------------------------------------------------

// Stage chunk Q (3 dL slabs = 5760 floats = 1440 float4) of wcb_b into LDS.
#define STAGE(Q)                                                          \
  __syncthreads();                                                        \
  {                                                                       \
    const float4* src4 = (const float4*)(wcb_b + (Q)*5760);               \
    float4* dst4 = (float4*)ldsw;                                         \
    dst4[tid]       = src4[tid];                                          \
    dst4[tid + 512] = src4[tid + 512];                                    \
    if (tid < 416) dst4[tid + 1024] = src4[tid + 1024];                   \
  }                                                                       \
  __syncthreads();

// u for one dL from LDS slab SLAB (0..2): 2 half-chains per node.
#define UCOMP(SLAB)                                                       \
  {                                                                       \
    float a0=0.f, a1=0.f, b0=0.f, b1=0.f;                                 \
    const float* wp = ldsw + (SLAB)*1920 + c;                             \
    _Pragma("unroll")                                                     \
    for (int k = 0; k < 15; ++k){                                         \
      const float w0 = wp[k*64];                                          \
      const float w1 = wp[(k+15)*64];                                     \
      a0 = fmaf(nabA[k],    w0, a0);                                      \
      a1 = fmaf(nabA[k+15], w1, a1);                                      \
      b0 = fmaf(nabB[k],    w0, b0);                                      \
      b1 = fmaf(nabB[k+15], w1, b1);                                      \
    }                                                                     \
    uA = a0 + a1; uB = b0 + b1;                                           \
  }

// one tensor-product entry: o[S] += cw[DL,M,S] * u * v[M]   (literal indices)
#define E(DL,M,S)                                                         \
  {                                                                       \
    const float cc = cw[((DL)*9+(M))*9+(S)];                              \
    oA[S] = fmaf(cc * uA, vA[M], oA[S]);                                  \
    oB[S] = fmaf(cc * uB, vB[M], oB[S]);                                  \
  }

#define LD9(dst, p) { dst[0]=(p)[0]; dst[1]=(p)[1]; dst[2]=(p)[2];        \
                      dst[3]=(p)[3]; dst[4]=(p)[4]; dst[5]=(p)[5];        \
                      dst[6]=(p)[6]; dst[7]=(p)[7]; dst[8]=(p)[8]; }
#define ST9(p, src) { (p)[0]=src[0]; (p)[1]=src[1]; (p)[2]=src[2];        \
                      (p)[3]=src[3]; (p)[4]=src[4]; (p)[5]=src[5];        \
                      (p)[6]=src[6]; (p)[7]=src[7]; (p)[8]=src[8]; }

__global__ __launch_bounds__(512)
void nn3b_main_kernel(const float* __restrict__ nbody,
                      const float* __restrict__ cw,
                      const float* __restrict__ wcB,
                      const float* __restrict__ nab,
                      float* __restrict__ out)
{
  __shared__ __align__(16) float ldsw[5760];   // 23,040 B: one 3-dL chunk

  const int tid = threadIdx.x;
  const int c   = tid & 63;
  const int g   = __builtin_amdgcn_readfirstlane((int)(tid >> 6)); // SGPR
  const int nA  = blockIdx.x * 16 + g * 2;   // this wave's node pair
  const int nB  = nA + 1;

  float oA[9] = {0,0,0,0,0,0,0,0,0};
  float oB[9] = {0,0,0,0,0,0,0,0,0};

  const float* nabA = nab + (size_t)nA * 32;
  const float* nabB = nab + (size_t)nB * 32;

  #pragma unroll 1   // keep body-order loop rolled: 3x smaller code
  for (int b = 0; b < 3; ++b){
    float vA[9], vB[9];
    {
      const float* pA = nbody + ((size_t)b*N_NODES + nA)*576 + c*9;
      const float* pB = nbody + ((size_t)b*N_NODES + nB)*576 + c*9;
      LD9(vA, pA);
      LD9(vB, pB);
    }
    const float* wcb_b = wcB + b*(9*30*64);
    float uA, uB;

    STAGE(0)                                    // dL 0,1,2
    UCOMP(0)
    E(0,0,0) E(0,1,1) E(0,2,2) E(0,3,3) E(0,4,4) E(0,5,5) E(0,6,6) E(0,7,7) E(0,8,8)
    UCOMP(1)
    E(1,0,1) E(1,1,0) E(1,3,4) E(1,2,5) E(1,1,6) E(1,1,8) E(1,4,3) E(1,5,2) E(1,6,1) E(1,8,1)
    UCOMP(2)
    E(2,0,2) E(2,2,0) E(2,1,5) E(2,3,7) E(2,2,6) E(2,5,1) E(2,7,3) E(2,6,2)

    STAGE(1)                                    // dL 3,4,5
    UCOMP(0)
    E(3,0,3) E(3,3,0) E(3,1,4) E(3,2,7) E(3,3,6) E(3,3,8) E(3,4,1) E(3,7,2) E(3,6,3) E(3,8,3)
    UCOMP(1)
    E(4,0,4) E(4,4,0) E(4,1,3) E(4,3,1) E(4,6,4) E(4,4,6) E(4,5,7) E(4,7,5)
    UCOMP(2)
    E(5,0,5) E(5,5,0) E(5,1,2) E(5,2,1) E(5,6,5) E(5,5,6) E(5,5,8) E(5,8,5) E(5,4,7) E(5,7,4)

    STAGE(2)                                    // dL 6,7,8
    UCOMP(0)
    E(6,0,6) E(6,6,0) E(6,1,1) E(6,2,2) E(6,3,3) E(6,6,6) E(6,5,5) E(6,7,7) E(6,4,4) E(6,8,8)
    UCOMP(1)
    E(7,0,7) E(7,7,0) E(7,2,3) E(7,3,2) E(7,6,7) E(7,7,6) E(7,7,8) E(7,8,7) E(7,4,5) E(7,5,4)
    UCOMP(2)
    E(8,0,8) E(8,8,0) E(8,1,1) E(8,3,3) E(8,6,8) E(8,8,6) E(8,5,5) E(8,7,7)
  }

  {
    float* pA = out + (size_t)nA*576 + c*9;
    float* pB = out + (size_t)nB*576 + c*9;
    ST9(pA, oA);
    ST9(pB, oB);
  }
}

extern "C" void kernel_launch(void* const* d_in, const int* in_sizes, int n_in,
                              void* d_out, int out_size, void* d_ws, size_t ws_size,
                              hipStream_t stream)
{
  const float* nbody     = (const float*)d_in[0];  // (3, 20000, 64, 9) f32
  const float* node_attr = (const float*)d_in[1];  // (20000, 10) f32
  const float* W_chem    = (const float*)d_in[2];  // (30, 1728) f32
  const float* wbody     = (const float*)d_in[3];  // (3, 1) f32
  float* out = (float*)d_out;                      // (20000, 64, 9) f32

  float* cw  = (float*)d_ws;          // 1024 f
  float* wcB = cw + CW_FLOATS;        // 51840 f
  float* nab = wcB + WCB_FLOATS;      // 640000 f   (total ~2.65 MiB of ws)

  const int init_items  = CW_FLOATS + WCB_FLOATS + NAB_FLOATS;
  const int init_blocks = (init_items + 255) / 256;
  nn3b_init_kernel<<<init_blocks, 256, 0, stream>>>(node_attr, W_chem, wbody, cw, wcB, nab);

  nn3b_main_kernel<<<N_NODES/16, 512, 0, stream>>>(nbody, cw, wcB, nab, out);
}